// Round 7
// baseline (300.652 us; speedup 1.0000x reference)
//
#include <hip/hip_runtime.h>

#define NN 50000
#define NP 50176        // padded node stride (multiple of 256)
#define TT 518
#define KC 32
#define LL 163
#define HH 128
#define EE 1600000
#define NB 196          // node blocks: 196*256 = 50176 >= NN
#define NCOPY 8

// ---- chunked-LDS scatter (no global atomics) ----
#define CKN 4           // node chunks
#define CSZ 12544       // nodes/chunk (4*12544 = 50176), LDS acc = 50176 B
#define PSL 128         // edge slices (partials per chunk)
#define GSC (CKN*PSL)   // 512 blocks
#define ESL (EE/PSL)    // 12500 edges per slice (divisible by 4)
#define PQ 4            // p-quarters for the two-stage partial reduction

// ---- conv8: LDS-tile conv, 128-node rows ----
// R1 diagnosis (conv2) was right: LDS staging reads x once and compute is
// cheap; it failed ONLY on 64B HBM granules (16-node rows -> 1.1 TB/s).
// R3/R6 proved the register-window alternative is allocator-capped at
// VGPR=128 (loads chained, 1.57 TB/s).  conv8 = conv2 structure with
// 128-node rows (512B granules) + global_load_lds (deep vmcnt queue, no
// VGPR window at all).
#define CN8 128         // nodes per block (one thread per node)
#define NB8 392         // 392*128 = 50176
#define LG8 6           // l-groups: grid = NB8*LG8 = 2352 blocks
#define LPB8 28         // l's per group (6*28 = 168 >= 163)
#define SPAN8 113       // t-span: 3*(LPB8-1)+32; LDS tile 113*128*4 = 57.9 KB
#define VS 16           // v accumulator stripes
#define VSTR 192        // stripe stride (>= LL, 16B-aligned)

#define GLOAD_LDS4(gsrc, ldst)                                        \
  __builtin_amdgcn_global_load_lds(                                   \
      (const __attribute__((address_space(1))) void*)(gsrc),          \
      (__attribute__((address_space(3))) void*)(ldst), 4, 0, 0)

// deg partials: block (chunk=b&3, p=b>>2) scans slice p, bins col hits into
// LDS, flushes private partial with plain stores.  Software-pipelined.
__global__ __launch_bounds__(256) void k_deg_part(const int* __restrict__ col,
                                                  const float* __restrict__ ea,
                                                  float* __restrict__ part) {
  __shared__ float acc[CSZ];
  int tid = threadIdx.x;
  for (int j = tid; j < CSZ; j += 256) acc[j] = 0.f;
  __syncthreads();
  int chunk = blockIdx.x & (CKN - 1);
  int base = chunk * CSZ;
  const int4*   c4p = (const int4*)col + (blockIdx.x >> 2) * (ESL / 4);
  const float4* a4p = (const float4*)ea + (blockIdx.x >> 2) * (ESL / 4);
  int i = tid;
  bool valid = i < ESL / 4;
  int4 c4; float4 a4;
  if (valid) { c4 = c4p[i]; a4 = a4p[i]; }
  while (valid) {
    int inext = i + 256;
    bool vnext = inext < ESL / 4;
    int4 c4n; float4 a4n;
    if (vnext) { c4n = c4p[inext]; a4n = a4p[inext]; }
    unsigned jx = (unsigned)(c4.x - base);
    unsigned jy = (unsigned)(c4.y - base);
    unsigned jz = (unsigned)(c4.z - base);
    unsigned jw = (unsigned)(c4.w - base);
    if (jx < CSZ) atomicAdd(&acc[jx], a4.x);
    if (jy < CSZ) atomicAdd(&acc[jy], a4.y);
    if (jz < CSZ) atomicAdd(&acc[jz], a4.z);
    if (jw < CSZ) atomicAdd(&acc[jw], a4.w);
    i = inext; valid = vnext; c4 = c4n; a4 = a4n;
  }
  __syncthreads();
  float* out = part + (size_t)blockIdx.x * CSZ;
  for (int j = tid; j < CSZ; j += 256) out[j] = acc[j];
}

// stage-A partial reduction: block (nb, q) sums 32 slices for 256 nodes.
__global__ __launch_bounds__(256) void k_psum(const float* __restrict__ part,
                                              float* __restrict__ part2) {
  int b = blockIdx.x;
  int nb = b % NB, q = b / NB;     // q in 0..3
  int i = nb * 256 + threadIdx.x;
  if (i >= NN) return;
  int chunk = i / CSZ, j = i - chunk * CSZ;
  const float* base = part + (size_t)chunk * CSZ + j;
  int p0 = q * (PSL / PQ);
  float s0 = 0.f, s1 = 0.f, s2 = 0.f, s3 = 0.f;
#pragma unroll
  for (int p = 0; p < PSL / PQ; p += 4) {
    s0 += base[(size_t)(p0 + p + 0) * (CKN * CSZ)];
    s1 += base[(size_t)(p0 + p + 1) * (CKN * CSZ)];
    s2 += base[(size_t)(p0 + p + 2) * (CKN * CSZ)];
    s3 += base[(size_t)(p0 + p + 3) * (CKN * CSZ)];
  }
  part2[(size_t)q * NP + i] = (s0 + s1) + (s2 + s3);
}

// dinv[i] = rsqrt(1 + sum_q part2[q][i]); also zeroes v16 (saves a dispatch)
__global__ __launch_bounds__(256) void k_dinv3(const float* __restrict__ part2,
                                               float* __restrict__ dinv,
                                               float* __restrict__ v16) {
  int tid = threadIdx.x;
  if (blockIdx.x < (VS * VSTR) / 256) v16[blockIdx.x * 256 + tid] = 0.f;
  int i = blockIdx.x * 256 + tid;
  if (i >= NN) return;
  float s = part2[i] + part2[NP + i] + part2[2 * NP + i] + part2[3 * NP + i];
  dinv[i] = rsqrtf(1.0f + s);
}

// coef partials: acc[row] += ea * dinv[col]; dinv[row] folded into k_csum3.
__global__ __launch_bounds__(256) void k_coef_part(const int* __restrict__ row,
                                                   const int* __restrict__ col,
                                                   const float* __restrict__ ea,
                                                   const float* __restrict__ dinv,
                                                   float* __restrict__ part) {
  __shared__ float acc[CSZ];
  int tid = threadIdx.x;
  for (int j = tid; j < CSZ; j += 256) acc[j] = 0.f;
  __syncthreads();
  int chunk = blockIdx.x & (CKN - 1);
  int base = chunk * CSZ;
  const int4*   r4p = (const int4*)row + (blockIdx.x >> 2) * (ESL / 4);
  const int4*   c4p = (const int4*)col + (blockIdx.x >> 2) * (ESL / 4);
  const float4* a4p = (const float4*)ea + (blockIdx.x >> 2) * (ESL / 4);
  int i = tid;
  bool valid = i < ESL / 4;
  int4 r4, c4; float4 a4;
  if (valid) { r4 = r4p[i]; c4 = c4p[i]; a4 = a4p[i]; }
  while (valid) {
    int inext = i + 256;
    bool vnext = inext < ESL / 4;
    int4 r4n, c4n; float4 a4n;
    if (vnext) { r4n = r4p[inext]; c4n = c4p[inext]; a4n = a4p[inext]; }
    float dx = dinv[c4.x], dy = dinv[c4.y], dz = dinv[c4.z], dw = dinv[c4.w];
    unsigned jx = (unsigned)(r4.x - base);
    unsigned jy = (unsigned)(r4.y - base);
    unsigned jz = (unsigned)(r4.z - base);
    unsigned jw = (unsigned)(r4.w - base);
    if (jx < CSZ) atomicAdd(&acc[jx], a4.x * dx);
    if (jy < CSZ) atomicAdd(&acc[jy], a4.y * dy);
    if (jz < CSZ) atomicAdd(&acc[jz], a4.z * dz);
    if (jw < CSZ) atomicAdd(&acc[jw], a4.w * dw);
    i = inext; valid = vnext; r4 = r4n; c4 = c4n; a4 = a4n;
  }
  __syncthreads();
  float* out = part + (size_t)blockIdx.x * CSZ;
  for (int j = tid; j < CSZ; j += 256) out[j] = acc[j];
}

// c[i] = dinv[i]^2 + dinv[i] * sum_q part2[q][i]
__global__ __launch_bounds__(256) void k_csum3(const float* __restrict__ part2,
                                               const float* __restrict__ dinv,
                                               float* __restrict__ c) {
  int i = blockIdx.x * 256 + threadIdx.x;
  if (i >= NN) return;
  float s = part2[i] + part2[NP + i] + part2[2 * NP + i] + part2[3 * NP + i];
  float di = dinv[i];
  c[i] = di * di + di * s;
}

// ---- fallback path (global-atomic version) if ws is too small ----
__global__ __launch_bounds__(256) void k_deg(const int* __restrict__ col,
                                             const float* __restrict__ ea,
                                             float* __restrict__ deg8) {
  int i = blockIdx.x * 256 + threadIdx.x;
  float* d = deg8 + (blockIdx.x & 7) * NP;
  if (i < EE / 4) {
    int4   c4 = ((const int4*)col)[i];
    float4 a4 = ((const float4*)ea)[i];
    atomicAdd(&d[c4.x], a4.x);
    atomicAdd(&d[c4.y], a4.y);
    atomicAdd(&d[c4.z], a4.z);
    atomicAdd(&d[c4.w], a4.w);
  }
}
__global__ __launch_bounds__(256) void k_dinv(const float* __restrict__ deg8,
                                              float* __restrict__ dinv) {
  int i = blockIdx.x * 256 + threadIdx.x;
  if (i < NN) {
    float s = 1.0f;
#pragma unroll
    for (int j = 0; j < NCOPY; ++j) s += deg8[j * NP + i];
    dinv[i] = rsqrtf(s);
  }
}
__global__ __launch_bounds__(256) void k_coef(const int* __restrict__ row,
                                              const int* __restrict__ col,
                                              const float* __restrict__ ea,
                                              const float* __restrict__ dinv,
                                              float* __restrict__ coef8) {
  int i = blockIdx.x * 256 + threadIdx.x;
  float* cf = coef8 + (blockIdx.x & 7) * NP;
  if (i < EE / 4) {
    int4   r4 = ((const int4*)row)[i];
    int4   c4 = ((const int4*)col)[i];
    float4 a4 = ((const float4*)ea)[i];
    atomicAdd(&cf[r4.x], a4.x * dinv[c4.x] * dinv[r4.x]);
    atomicAdd(&cf[r4.y], a4.y * dinv[c4.y] * dinv[r4.y]);
    atomicAdd(&cf[r4.z], a4.z * dinv[c4.z] * dinv[r4.z]);
    atomicAdd(&cf[r4.w], a4.w * dinv[c4.w] * dinv[r4.w]);
  }
}
__global__ __launch_bounds__(256) void k_csum(const float* __restrict__ coef8,
                                              const float* __restrict__ dinv,
                                              float* __restrict__ c) {
  int i = blockIdx.x * 256 + threadIdx.x;
  if (i < NN) {
    float di = dinv[i];
    float s = di * di;
#pragma unroll
    for (int j = 0; j < NCOPY; ++j) s += coef8[j * NP + i];
    c[i] = s;
  }
}

// v[l] += sum_n c[n]*relu(conv(x,w)+b)[l].
// conv8: block (nb, gq) = 128 nodes x 28 l's.  Stage xtile[113][128] via
// global_load_lds (512B coalesced rows, no VGPR window -> immune to the
// allocator chaining that capped conv3/4/7 at 1.57 TB/s), then t-major
// compute from LDS (conv2-verified ulo/uhi pattern; bank = tid%32, 2
// lanes/bank = free).  57.9 KB LDS -> 2 blocks/CU: block A computes while
// block B stages.  Traffic: x 1.31x (136 MB) + w 6x (38 MB).
__global__ __launch_bounds__(128, 1) void k_conv8(const float* __restrict__ x,
                                                  const float* __restrict__ cw,
                                                  const float* __restrict__ cb,
                                                  const float* __restrict__ c,
                                                  float* __restrict__ v16) {
  __shared__ float xtile[SPAN8 * CN8];   // 57,856 B
  __shared__ float vloc[LPB8];
  int tid = threadIdx.x;
  if (tid < LPB8) vloc[tid] = 0.f;

  int nb = blockIdx.x % NB8;
  int gq = blockIdx.x / NB8;       // 0..5
  int n0 = nb * CN8;
  int n = n0 + tid;
  int nc = n < NN ? n : NN - 1;    // clamp for safe loads; cn=0 kills contrib
  float cn = n < NN ? c[n] : 0.f;
  float bn = cb[nc];

  // per-node weights (128B-stride gather; R5 proved this is NOT the limiter)
  float w[KC];
  const float4* w4 = (const float4*)(cw + (size_t)nc * KC);
#pragma unroll
  for (int k = 0; k < KC / 4; ++k) {
    float4 t = w4[k];
    w[4 * k] = t.x; w[4 * k + 1] = t.y; w[4 * k + 2] = t.z; w[4 * k + 3] = t.w;
  }

  // stage tile: rows t0..t0+112, 128 nodes each.  LDS dest = wave-uniform
  // base + lane*4 (linear); global src per-lane.  Clamp t (pollutes only
  // l>=163, see proof in comments below) and node (cn=0 nodes only).
  int t0 = 3 * LPB8 * gq;          // 84*gq
  int wbase = tid & 64;            // wave-uniform half offset
  const float* xg = x + nc;        // per-lane source column
#pragma unroll 4
  for (int r = 0; r < SPAN8; ++r) {
    int t = t0 + r;
    t = t < TT ? t : TT - 1;       // only gq=5 clamps; feeds only u>=23 -> l>=163
    GLOAD_LDS4(xg + (size_t)t * NN, &xtile[r * CN8 + wbase]);
  }
  __syncthreads();                 // drains vmcnt (global_load_lds) + joins waves

  // t-major sweep: acc[u] += xtile[r][tid] * w[r-3u], all indices static.
  float acc[LPB8];
#pragma unroll
  for (int u = 0; u < LPB8; ++u) acc[u] = 0.f;
#pragma unroll
  for (int r = 0; r < SPAN8; ++r) {
    float xt = xtile[r * CN8 + tid];
    const int ulo = (r <= 31) ? 0 : (r - 29) / 3;        // ceil((r-31)/3)
    const int uhi = (r / 3 < LPB8 - 1) ? r / 3 : LPB8 - 1;
#pragma unroll
    for (int u = ulo; u <= uhi; ++u) acc[u] += xt * w[r - 3 * u];
  }

  int lane = tid & 63;
#pragma unroll
  for (int u = 0; u < LPB8; ++u) {
    float h = acc[u] + bn;
    h = h > 0.f ? h : 0.f;
    float val = cn * h;
    val += __shfl_xor(val, 1, 64);
    val += __shfl_xor(val, 2, 64);
    val += __shfl_xor(val, 4, 64);
    val += __shfl_xor(val, 8, 64);
    val += __shfl_xor(val, 16, 64);
    val += __shfl_xor(val, 32, 64);
    if (lane == 0) atomicAdd(&vloc[u], val);   // 2 waves -> 2 adds per l
  }
  __syncthreads();
  float* vdst = v16 + (blockIdx.x & (VS - 1)) * VSTR;
  if (tid < LPB8) {
    int l = LPB8 * gq + tid;
    if (l < LL) atomicAdd(&vdst[l], vloc[tid]);
  }
}

// out[h] = (sum_l (sum_j v16[j][l]) * W[l][h]) / N + gcn_b[h]
__global__ __launch_bounds__(128) void k_out(const float* __restrict__ v16,
                                             const float* __restrict__ W,
                                             const float* __restrict__ b,
                                             float* __restrict__ out) {
  __shared__ float vs[LL];
  int h = threadIdx.x;
  for (int l = h; l < LL; l += 128) {
    float s = 0.f;
#pragma unroll
    for (int j = 0; j < VS; ++j) s += v16[j * VSTR + l];
    vs[l] = s;
  }
  __syncthreads();
  float s = 0.f;
  for (int l = 0; l < LL; ++l) s += vs[l] * W[l * HH + h];
  out[h] = s * (1.0f / NN) + b[h];
}

extern "C" void kernel_launch(void* const* d_in, const int* in_sizes, int n_in,
                              void* d_out, int out_size, void* d_ws, size_t ws_size,
                              hipStream_t stream) {
  const float* x  = (const float*)d_in[0];
  const int*   ei = (const int*)d_in[1];
  const float* ea = (const float*)d_in[2];
  const float* cw = (const float*)d_in[3];
  const float* cb = (const float*)d_in[4];
  const float* gW = (const float*)d_in[5];
  const float* gb = (const float*)d_in[6];
  float* out = (float*)d_out;

  const int* row = ei;
  const int* col = ei + EE;
  float* ws = (float*)d_ws;

  size_t need_new = ((size_t)GSC * CSZ + VS * VSTR + (2 + PQ) * NP) * sizeof(float);
  if (ws_size >= need_new) {
    float* part  = ws;                          // GSC*CSZ floats (reused deg->coef)
    float* v16   = ws + (size_t)GSC * CSZ;      // VS*VSTR floats
    float* dinv  = v16 + VS * VSTR;             // NP floats
    float* c     = dinv + NP;                   // NP floats
    float* part2 = c + NP;                      // PQ*NP floats
    k_deg_part <<<GSC, 256, 0, stream>>>(col, ea, part);
    k_psum     <<<NB * PQ, 256, 0, stream>>>(part, part2);
    k_dinv3    <<<NB, 256, 0, stream>>>(part2, dinv, v16);
    k_coef_part<<<GSC, 256, 0, stream>>>(row, col, ea, dinv, part);
    k_psum     <<<NB * PQ, 256, 0, stream>>>(part, part2);
    k_csum3    <<<NB, 256, 0, stream>>>(part2, dinv, c);
    k_conv8    <<<NB8 * LG8, 128, 0, stream>>>(x, cw, cb, c, v16);
    k_out      <<<1, 128, 0, stream>>>(v16, gW, gb, out);
  } else {
    float* deg8  = ws;
    float* coef8 = ws + NCOPY * NP;
    float* v16   = ws + 2 * NCOPY * NP;
    float* dinv  = v16 + VS * VSTR;
    float* c     = dinv + NP;
    hipMemsetAsync(deg8, 0, (2 * NCOPY * NP + VS * VSTR) * sizeof(float), stream);
    int egrid = (EE / 4 + 255) / 256;
    k_deg  <<<egrid, 256, 0, stream>>>(col, ea, deg8);
    k_dinv <<<NB, 256, 0, stream>>>(deg8, dinv);
    k_coef <<<egrid, 256, 0, stream>>>(row, col, ea, dinv, coef8);
    k_csum <<<NB, 256, 0, stream>>>(coef8, dinv, c);
    k_conv8<<<NB8 * LG8, 128, 0, stream>>>(x, cw, cb, c, v16);
    k_out  <<<1, 128, 0, stream>>>(v16, gW, gb, out);
  }
}

// Round 8
// 299.748 us; speedup vs baseline: 1.0030x; 1.0030x over previous
//
#include <hip/hip_runtime.h>

#define NN 50000
#define NP 50176        // padded node stride (multiple of 256)
#define TT 518
#define KC 32
#define LL 163
#define HH 128
#define EE 1600000
#define NB 196          // node blocks: 196*256 = 50176 >= NN
#define NCOPY 8

// ---- chunked-LDS scatter (no global atomics) ----
#define CKN 4           // node chunks
#define CSZ 12544       // nodes/chunk (4*12544 = 50176), LDS acc = 50176 B
#define PSL 128         // edge slices (partials per chunk)
#define GSC (CKN*PSL)   // 512 blocks
#define ESL (EE/PSL)    // 12500 edges per slice (divisible by 4)
#define PQ 4            // p-quarters for the two-stage partial reduction

// ---- conv9: LDS-tile conv, 256-node rows, width-16 global_load_lds ----
// Failure ledger: reg-window >53 floats -> allocator chains loads (conv3/4/7,
// VGPR hard-capped at 128, 1.57 TB/s).  LDS tile + width-4 gload_lds ->
// LDS-direct dword write wall (conv8, 1.5 TB/s; same wall as m93's 517 TF,
// fixed by width 16 in m97 -> +69%).  LDS tile + 64B rows -> HBM granule
// wall (conv2, 1.1 TB/s).  conv9 avoids all three: no VGPR window, 1KB per
// staging inst (one global_load_lds_dwordx4 per 256-node row per wave).
#define CN9 256         // nodes per block (thread = node)
#define LG9 6           // l-groups: grid = NB*LG9 = 1176 blocks
#define LPB9 28         // l's per group (6*28 = 168 >= 163)
#define SPAN9 113       // t-span: 3*(LPB9-1)+32; tile 113*256*4 = 113 KB LDS
#define RPW 29          // rows per wave (4*29 = 116 >= 113)
#define VS 16           // v accumulator stripes
#define VSTR 192        // stripe stride (>= LL, 16B-aligned)

#define GLOAD_LDS16(gsrc, ldst)                                       \
  __builtin_amdgcn_global_load_lds(                                   \
      (const __attribute__((address_space(1))) void*)(gsrc),          \
      (__attribute__((address_space(3))) void*)(ldst), 16, 0, 0)

// deg partials: block (chunk=b&3, p=b>>2) scans slice p, bins col hits into
// LDS, flushes private partial with plain stores.  Software-pipelined.
__global__ __launch_bounds__(256) void k_deg_part(const int* __restrict__ col,
                                                  const float* __restrict__ ea,
                                                  float* __restrict__ part) {
  __shared__ float acc[CSZ];
  int tid = threadIdx.x;
  for (int j = tid; j < CSZ; j += 256) acc[j] = 0.f;
  __syncthreads();
  int chunk = blockIdx.x & (CKN - 1);
  int base = chunk * CSZ;
  const int4*   c4p = (const int4*)col + (blockIdx.x >> 2) * (ESL / 4);
  const float4* a4p = (const float4*)ea + (blockIdx.x >> 2) * (ESL / 4);
  int i = tid;
  bool valid = i < ESL / 4;
  int4 c4; float4 a4;
  if (valid) { c4 = c4p[i]; a4 = a4p[i]; }
  while (valid) {
    int inext = i + 256;
    bool vnext = inext < ESL / 4;
    int4 c4n; float4 a4n;
    if (vnext) { c4n = c4p[inext]; a4n = a4p[inext]; }
    unsigned jx = (unsigned)(c4.x - base);
    unsigned jy = (unsigned)(c4.y - base);
    unsigned jz = (unsigned)(c4.z - base);
    unsigned jw = (unsigned)(c4.w - base);
    if (jx < CSZ) atomicAdd(&acc[jx], a4.x);
    if (jy < CSZ) atomicAdd(&acc[jy], a4.y);
    if (jz < CSZ) atomicAdd(&acc[jz], a4.z);
    if (jw < CSZ) atomicAdd(&acc[jw], a4.w);
    i = inext; valid = vnext; c4 = c4n; a4 = a4n;
  }
  __syncthreads();
  float* out = part + (size_t)blockIdx.x * CSZ;
  for (int j = tid; j < CSZ; j += 256) out[j] = acc[j];
}

// stage-A partial reduction: block (nb, q) sums 32 slices for 256 nodes.
__global__ __launch_bounds__(256) void k_psum(const float* __restrict__ part,
                                              float* __restrict__ part2) {
  int b = blockIdx.x;
  int nb = b % NB, q = b / NB;     // q in 0..3
  int i = nb * 256 + threadIdx.x;
  if (i >= NN) return;
  int chunk = i / CSZ, j = i - chunk * CSZ;
  const float* base = part + (size_t)chunk * CSZ + j;
  int p0 = q * (PSL / PQ);
  float s0 = 0.f, s1 = 0.f, s2 = 0.f, s3 = 0.f;
#pragma unroll
  for (int p = 0; p < PSL / PQ; p += 4) {
    s0 += base[(size_t)(p0 + p + 0) * (CKN * CSZ)];
    s1 += base[(size_t)(p0 + p + 1) * (CKN * CSZ)];
    s2 += base[(size_t)(p0 + p + 2) * (CKN * CSZ)];
    s3 += base[(size_t)(p0 + p + 3) * (CKN * CSZ)];
  }
  part2[(size_t)q * NP + i] = (s0 + s1) + (s2 + s3);
}

// dinv[i] = rsqrt(1 + sum_q part2[q][i]); also zeroes v16 (saves a dispatch)
__global__ __launch_bounds__(256) void k_dinv3(const float* __restrict__ part2,
                                               float* __restrict__ dinv,
                                               float* __restrict__ v16) {
  int tid = threadIdx.x;
  if (blockIdx.x < (VS * VSTR) / 256) v16[blockIdx.x * 256 + tid] = 0.f;
  int i = blockIdx.x * 256 + tid;
  if (i >= NN) return;
  float s = part2[i] + part2[NP + i] + part2[2 * NP + i] + part2[3 * NP + i];
  dinv[i] = rsqrtf(1.0f + s);
}

// coef partials: acc[row] += ea * dinv[col]; dinv[row] folded into k_csum3.
__global__ __launch_bounds__(256) void k_coef_part(const int* __restrict__ row,
                                                   const int* __restrict__ col,
                                                   const float* __restrict__ ea,
                                                   const float* __restrict__ dinv,
                                                   float* __restrict__ part) {
  __shared__ float acc[CSZ];
  int tid = threadIdx.x;
  for (int j = tid; j < CSZ; j += 256) acc[j] = 0.f;
  __syncthreads();
  int chunk = blockIdx.x & (CKN - 1);
  int base = chunk * CSZ;
  const int4*   r4p = (const int4*)row + (blockIdx.x >> 2) * (ESL / 4);
  const int4*   c4p = (const int4*)col + (blockIdx.x >> 2) * (ESL / 4);
  const float4* a4p = (const float4*)ea + (blockIdx.x >> 2) * (ESL / 4);
  int i = tid;
  bool valid = i < ESL / 4;
  int4 r4, c4; float4 a4;
  if (valid) { r4 = r4p[i]; c4 = c4p[i]; a4 = a4p[i]; }
  while (valid) {
    int inext = i + 256;
    bool vnext = inext < ESL / 4;
    int4 r4n, c4n; float4 a4n;
    if (vnext) { r4n = r4p[inext]; c4n = c4p[inext]; a4n = a4p[inext]; }
    float dx = dinv[c4.x], dy = dinv[c4.y], dz = dinv[c4.z], dw = dinv[c4.w];
    unsigned jx = (unsigned)(r4.x - base);
    unsigned jy = (unsigned)(r4.y - base);
    unsigned jz = (unsigned)(r4.z - base);
    unsigned jw = (unsigned)(r4.w - base);
    if (jx < CSZ) atomicAdd(&acc[jx], a4.x * dx);
    if (jy < CSZ) atomicAdd(&acc[jy], a4.y * dy);
    if (jz < CSZ) atomicAdd(&acc[jz], a4.z * dz);
    if (jw < CSZ) atomicAdd(&acc[jw], a4.w * dw);
    i = inext; valid = vnext; r4 = r4n; c4 = c4n; a4 = a4n;
  }
  __syncthreads();
  float* out = part + (size_t)blockIdx.x * CSZ;
  for (int j = tid; j < CSZ; j += 256) out[j] = acc[j];
}

// c[i] = dinv[i]^2 + dinv[i] * sum_q part2[q][i]
__global__ __launch_bounds__(256) void k_csum3(const float* __restrict__ part2,
                                               const float* __restrict__ dinv,
                                               float* __restrict__ c) {
  int i = blockIdx.x * 256 + threadIdx.x;
  if (i >= NN) return;
  float s = part2[i] + part2[NP + i] + part2[2 * NP + i] + part2[3 * NP + i];
  float di = dinv[i];
  c[i] = di * di + di * s;
}

// ---- fallback path (global-atomic version) if ws is too small ----
__global__ __launch_bounds__(256) void k_deg(const int* __restrict__ col,
                                             const float* __restrict__ ea,
                                             float* __restrict__ deg8) {
  int i = blockIdx.x * 256 + threadIdx.x;
  float* d = deg8 + (blockIdx.x & 7) * NP;
  if (i < EE / 4) {
    int4   c4 = ((const int4*)col)[i];
    float4 a4 = ((const float4*)ea)[i];
    atomicAdd(&d[c4.x], a4.x);
    atomicAdd(&d[c4.y], a4.y);
    atomicAdd(&d[c4.z], a4.z);
    atomicAdd(&d[c4.w], a4.w);
  }
}
__global__ __launch_bounds__(256) void k_dinv(const float* __restrict__ deg8,
                                              float* __restrict__ dinv) {
  int i = blockIdx.x * 256 + threadIdx.x;
  if (i < NN) {
    float s = 1.0f;
#pragma unroll
    for (int j = 0; j < NCOPY; ++j) s += deg8[j * NP + i];
    dinv[i] = rsqrtf(s);
  }
}
__global__ __launch_bounds__(256) void k_coef(const int* __restrict__ row,
                                              const int* __restrict__ col,
                                              const float* __restrict__ ea,
                                              const float* __restrict__ dinv,
                                              float* __restrict__ coef8) {
  int i = blockIdx.x * 256 + threadIdx.x;
  float* cf = coef8 + (blockIdx.x & 7) * NP;
  if (i < EE / 4) {
    int4   r4 = ((const int4*)row)[i];
    int4   c4 = ((const int4*)col)[i];
    float4 a4 = ((const float4*)ea)[i];
    atomicAdd(&cf[r4.x], a4.x * dinv[c4.x] * dinv[r4.x]);
    atomicAdd(&cf[r4.y], a4.y * dinv[c4.y] * dinv[r4.y]);
    atomicAdd(&cf[r4.z], a4.z * dinv[c4.z] * dinv[r4.z]);
    atomicAdd(&cf[r4.w], a4.w * dinv[c4.w] * dinv[r4.w]);
  }
}
__global__ __launch_bounds__(256) void k_csum(const float* __restrict__ coef8,
                                              const float* __restrict__ dinv,
                                              float* __restrict__ c) {
  int i = blockIdx.x * 256 + threadIdx.x;
  if (i < NN) {
    float di = dinv[i];
    float s = di * di;
#pragma unroll
    for (int j = 0; j < NCOPY; ++j) s += coef8[j * NP + i];
    c[i] = s;
  }
}

// v[l] += sum_n c[n]*relu(conv(x,w)+b)[l].
// conv9: block (nb, gq) = 256 nodes x 28 l's, tile xtile[113][256] staged
// with ONE global_load_lds_dwordx4 per row per wave (1 KB/inst, the
// coalescing sweet spot; wave wv stages rows wv*29..).  LDS dest is
// wave-uniform base (HW adds lane*16); global src per-lane = 4 nodes.
// Compute: thread = node, t-major sweep, LDS read stride 4B -> 2 lanes/bank
// (free).  113 KB LDS -> 1 block/CU, grid 1176 = ~4.6 rounds/CU.
__global__ __launch_bounds__(256, 1) void k_conv9(const float* __restrict__ x,
                                                  const float* __restrict__ cw,
                                                  const float* __restrict__ cb,
                                                  const float* __restrict__ c,
                                                  float* __restrict__ v16) {
  __shared__ float xtile[SPAN9 * CN9];   // 115,712 B
  __shared__ float vloc[LPB9];
  int tid = threadIdx.x;
  if (tid < LPB9) vloc[tid] = 0.f;

  int nb = blockIdx.x % NB;
  int gq = blockIdx.x / NB;        // 0..5
  int n0 = nb * CN9;
  int n = n0 + tid;
  int nc = n < NN ? n : NN - 1;    // clamp for safe loads; cn=0 kills contrib
  float cn = n < NN ? c[n] : 0.f;
  float bn = cb[nc];

  // per-node weights (128B-stride gather; R5 proved this is NOT the limiter)
  float w[KC];
  const float4* w4 = (const float4*)(cw + (size_t)nc * KC);
#pragma unroll
  for (int k = 0; k < KC / 4; ++k) {
    float4 t = w4[k];
    w[4 * k] = t.x; w[4 * k + 1] = t.y; w[4 * k + 2] = t.z; w[4 * k + 3] = t.w;
  }

  // stage tile: wave wv stages rows wv*RPW .. (uniform branch per wave).
  // Source per-lane: nodes n0+4*lane..+3, clamped to NN-4 (garbage lands in
  // slots whose cn=0).  t clamped to TT-1 (feeds only discarded l >= 163).
  int lane = tid & 63, wv = tid >> 6;
  int t0 = 3 * LPB9 * gq;          // 84*gq
  int nsrc = n0 + 4 * lane;
  if (nsrc > NN - 4) nsrc = NN - 4;
  const float* xg = x + nsrc;
#pragma unroll
  for (int i = 0; i < RPW; ++i) {
    int r = wv * RPW + i;
    if (r < SPAN9) {               // wave-uniform predicate
      int t = t0 + r;
      t = t < TT ? t : TT - 1;
      GLOAD_LDS16(xg + (size_t)t * NN, &xtile[r * CN9]);
    }
  }
  __syncthreads();                 // drains vmcnt + joins waves

  // t-major sweep: acc[u] += xtile[r][tid] * w[r-3u], all indices static.
  float acc[LPB9];
#pragma unroll
  for (int u = 0; u < LPB9; ++u) acc[u] = 0.f;
#pragma unroll
  for (int r = 0; r < SPAN9; ++r) {
    float xt = xtile[r * CN9 + tid];
    const int ulo = (r <= 31) ? 0 : (r - 29) / 3;        // ceil((r-31)/3)
    const int uhi = (r / 3 < LPB9 - 1) ? r / 3 : LPB9 - 1;
#pragma unroll
    for (int u = ulo; u <= uhi; ++u) acc[u] += xt * w[r - 3 * u];
  }

#pragma unroll
  for (int u = 0; u < LPB9; ++u) {
    float h = acc[u] + bn;
    h = h > 0.f ? h : 0.f;
    float val = cn * h;
    val += __shfl_xor(val, 1, 64);
    val += __shfl_xor(val, 2, 64);
    val += __shfl_xor(val, 4, 64);
    val += __shfl_xor(val, 8, 64);
    val += __shfl_xor(val, 16, 64);
    val += __shfl_xor(val, 32, 64);
    if (lane == 0) atomicAdd(&vloc[u], val);   // 4 waves -> 4 adds per l
  }
  __syncthreads();
  float* vdst = v16 + (blockIdx.x & (VS - 1)) * VSTR;
  if (tid < LPB9) {
    int l = LPB9 * gq + tid;
    if (l < LL) atomicAdd(&vdst[l], vloc[tid]);
  }
}

// out[h] = (sum_l (sum_j v16[j][l]) * W[l][h]) / N + gcn_b[h]
__global__ __launch_bounds__(128) void k_out(const float* __restrict__ v16,
                                             const float* __restrict__ W,
                                             const float* __restrict__ b,
                                             float* __restrict__ out) {
  __shared__ float vs[LL];
  int h = threadIdx.x;
  for (int l = h; l < LL; l += 128) {
    float s = 0.f;
#pragma unroll
    for (int j = 0; j < VS; ++j) s += v16[j * VSTR + l];
    vs[l] = s;
  }
  __syncthreads();
  float s = 0.f;
  for (int l = 0; l < LL; ++l) s += vs[l] * W[l * HH + h];
  out[h] = s * (1.0f / NN) + b[h];
}

extern "C" void kernel_launch(void* const* d_in, const int* in_sizes, int n_in,
                              void* d_out, int out_size, void* d_ws, size_t ws_size,
                              hipStream_t stream) {
  const float* x  = (const float*)d_in[0];
  const int*   ei = (const int*)d_in[1];
  const float* ea = (const float*)d_in[2];
  const float* cw = (const float*)d_in[3];
  const float* cb = (const float*)d_in[4];
  const float* gW = (const float*)d_in[5];
  const float* gb = (const float*)d_in[6];
  float* out = (float*)d_out;

  const int* row = ei;
  const int* col = ei + EE;
  float* ws = (float*)d_ws;

  size_t need_new = ((size_t)GSC * CSZ + VS * VSTR + (2 + PQ) * NP) * sizeof(float);
  if (ws_size >= need_new) {
    float* part  = ws;                          // GSC*CSZ floats (reused deg->coef)
    float* v16   = ws + (size_t)GSC * CSZ;      // VS*VSTR floats
    float* dinv  = v16 + VS * VSTR;             // NP floats
    float* c     = dinv + NP;                   // NP floats
    float* part2 = c + NP;                      // PQ*NP floats
    k_deg_part <<<GSC, 256, 0, stream>>>(col, ea, part);
    k_psum     <<<NB * PQ, 256, 0, stream>>>(part, part2);
    k_dinv3    <<<NB, 256, 0, stream>>>(part2, dinv, v16);
    k_coef_part<<<GSC, 256, 0, stream>>>(row, col, ea, dinv, part);
    k_psum     <<<NB * PQ, 256, 0, stream>>>(part, part2);
    k_csum3    <<<NB, 256, 0, stream>>>(part2, dinv, c);
    k_conv9    <<<NB * LG9, 256, 0, stream>>>(x, cw, cb, c, v16);
    k_out      <<<1, 128, 0, stream>>>(v16, gW, gb, out);
  } else {
    float* deg8  = ws;
    float* coef8 = ws + NCOPY * NP;
    float* v16   = ws + 2 * NCOPY * NP;
    float* dinv  = v16 + VS * VSTR;
    float* c     = dinv + NP;
    hipMemsetAsync(deg8, 0, (2 * NCOPY * NP + VS * VSTR) * sizeof(float), stream);
    int egrid = (EE / 4 + 255) / 256;
    k_deg  <<<egrid, 256, 0, stream>>>(col, ea, deg8);
    k_dinv <<<NB, 256, 0, stream>>>(deg8, dinv);
    k_coef <<<egrid, 256, 0, stream>>>(row, col, ea, dinv, coef8);
    k_csum <<<NB, 256, 0, stream>>>(coef8, dinv, c);
    k_conv9<<<NB * LG9, 256, 0, stream>>>(x, cw, cb, c, v16);
    k_out  <<<1, 128, 0, stream>>>(v16, gW, gb, out);
  }
}